// Round 15
// baseline (742.684 us; speedup 1.0000x reference)
//
#include <hip/hip_runtime.h>

typedef unsigned short u16;
typedef unsigned int u32;
using bf16x8 = __attribute__((ext_vector_type(8))) __bf16;
using f32x4  = __attribute__((ext_vector_type(4))) float;

typedef const void __attribute__((address_space(1)))* gas1p;
typedef void __attribute__((address_space(3)))* las3p;

__device__ __forceinline__ void gload16(const void* g, void* l) {
  __builtin_amdgcn_global_load_lds((gas1p)g, (las3p)l, 16, 0, 0);
}

__device__ __forceinline__ u16 f2bf(float f) {
  union { float f; unsigned u; } v; v.f = f;
  unsigned r = v.u + 0x7FFFu + ((v.u >> 16) & 1u);
  return (u16)(r >> 16);
}
__device__ __forceinline__ float bf2f(u16 h) {
  union { unsigned u; float f; } v; v.u = ((unsigned)h) << 16;
  return v.f;
}

// ---------------- x fp32 -> bf16 ----------------
__global__ __launch_bounds__(256)
void cvt_f32_bf16(const float4* __restrict__ in, uint2* __restrict__ out, int n4) {
  int i = blockIdx.x * 256 + threadIdx.x;
  if (i >= n4) return;
  float4 v = in[i];
  uint2 o;
  o.x = (unsigned)f2bf(v.x) | ((unsigned)f2bf(v.y) << 16);
  o.y = (unsigned)f2bf(v.z) | ((unsigned)f2bf(v.w) << 16);
  out[i] = o;
}

// ------- fused W transposes: Wq/Wk/Wv -> WqkvT, Wo -> WoT (one launch) -----
__global__ __launch_bounds__(256)
void transpose_all(const float* __restrict__ Wq, const float* __restrict__ Wk,
                   const float* __restrict__ Wv, const float* __restrict__ Wo,
                   u16* __restrict__ WqkvT, u16* __restrict__ WoT) {
  __shared__ float tile[32][33];
  const int bid = blockIdx.x;
  const float* in; u16* out; int C, R, bx, by;
  if (bid < 10240)      { in = Wq; out = WqkvT;                         R = 2560; C = 4096; bx = bid % 128;           by = bid / 128; }
  else if (bid < 12800) { in = Wk; out = WqkvT + (size_t)4096 * 2560;   R = 2560; C = 1024; bx = (bid - 10240) % 32;  by = (bid - 10240) / 32; }
  else if (bid < 15360) { in = Wv; out = WqkvT + (size_t)5120 * 2560;   R = 2560; C = 1024; bx = (bid - 12800) % 32;  by = (bid - 12800) / 32; }
  else                  { in = Wo; out = WoT;                           R = 4096; C = 2560; bx = (bid - 15360) % 80;  by = (bid - 15360) / 80; }
  const int tx = threadIdx.x & 31, ty = threadIdx.x >> 5;
  const int r0 = by * 32, c0 = bx * 32;
#pragma unroll
  for (int i = 0; i < 4; i++)
    tile[ty + i * 8][tx] = in[(size_t)(r0 + ty + i * 8) * C + c0 + tx];
  __syncthreads();
#pragma unroll
  for (int i = 0; i < 4; i++)
    out[(size_t)(c0 + ty + i * 8) * R + r0 + tx] = f2bf(tile[tx][ty + i * 8]);
}

// ---------------- V slice of QKV -> Vt (b,kv,d,l) bf16 ----------------
__global__ __launch_bounds__(256)
void transpose_v(const u16* __restrict__ QKV, u16* __restrict__ Vt) {
  __shared__ u16 tile[32][34];
  const int tx = threadIdx.x & 31, ty = threadIdx.x >> 5;
  const int l0 = blockIdx.x * 32, d0 = blockIdx.y * 32;
  const int bkv = blockIdx.z;
  const int b = bkv >> 3, kvh = bkv & 7;
#pragma unroll
  for (int i = 0; i < 4; i++)
    tile[ty + i * 8][tx] =
        QKV[(size_t)(b * 2048 + l0 + ty + i * 8) * 6144 + 5120 + kvh * 128 + d0 + tx];
  __syncthreads();
#pragma unroll
  for (int i = 0; i < 4; i++)
    Vt[((size_t)bkv * 128 + d0 + ty + i * 8) * 2048 + l0 + tx] = tile[tx][ty + i * 8];
}

// ---------------- RMSNorm + RoPE (+1/sqrt(128) folded into Q) ----------------
__global__ __launch_bounds__(256)
void norm_rope(const u16* __restrict__ QKV, const float* __restrict__ qw,
               const float* __restrict__ kw, const float* __restrict__ cosp,
               const float* __restrict__ sinp, u16* __restrict__ Qr,
               u16* __restrict__ Kr) {
  const int rid = blockIdx.x * 4 + (threadIdx.x >> 6);
  const int lane = threadIdx.x & 63;
  const int head = rid % 40;
  const int bl = rid / 40;               // b*2048 + l
  const int b = bl >> 11, l = bl & 2047;
  const u16* src; const float* w; u16* dst; float scale;
  if (head < 32) {
    src = QKV + (size_t)bl * 6144 + head * 128;
    w = qw;
    dst = Qr + ((size_t)(b * 32 + head) * 2048 + l) * 128;
    scale = 0.08838834764831845f;        // 1/sqrt(128)
  } else {
    const int kvh = head - 32;
    src = QKV + (size_t)bl * 6144 + 4096 + kvh * 128;
    w = kw;
    dst = Kr + ((size_t)(b * 8 + kvh) * 2048 + l) * 128;
    scale = 1.0f;
  }
  float lo = bf2f(src[lane]);
  float hi = bf2f(src[lane + 64]);
  float ss = lo * lo + hi * hi;
#pragma unroll
  for (int m = 1; m < 64; m <<= 1) ss += __shfl_xor(ss, m, 64);
  const float rstd = rsqrtf(ss * (1.0f / 128.0f) + 1e-6f) * scale;
  const float nlo = lo * rstd * w[lane];
  const float nhi = hi * rstd * w[lane + 64];
  const float* cb = cosp + (size_t)bl * 128;
  const float* sb = sinp + (size_t)bl * 128;
  dst[lane]      = f2bf(nlo * cb[lane]      - nhi * sb[lane]);
  dst[lane + 64] = f2bf(nhi * cb[lane + 64] + nlo * sb[lane + 64]);
}

// ====== BK=64 GEMM, 1 compute phase/K-tile (R8-proven structure) ===========
#define BAR __builtin_amdgcn_s_barrier()
#define WLG { asm volatile("s_waitcnt lgkmcnt(0)" ::: "memory");            \
              __builtin_amdgcn_sched_barrier(0); }
#define WVMn(n) asm volatile("s_waitcnt vmcnt(" #n ")" ::: "memory")
#define SP1 __builtin_amdgcn_s_setprio(1)
#define SP0 __builtin_amdgcn_s_setprio(0)

template <int MINW, int BM, int BN, int WM, int WN, typename CT>
__global__ __launch_bounds__(512, MINW)
void gemmT(const u16* __restrict__ A, const u16* __restrict__ Bt,
           CT* __restrict__ C, int N, int K, int MT) {
  extern __shared__ char smem[];
  constexpr int ASZ = BM * 128;
  constexpr int BSZ = BN * 128;
  constexpr int MI = BM / WM / 16;
  constexpr int NJF = BN / WN / 16;
  constexpr int NL = BM / 64 + (BN + 63) / 64;
  const int tid = threadIdx.x, lane = tid & 63, wid = tid >> 6;
  const int wm = wid / WN, wn = wid % WN;
  const int fr = lane & 15, fq = lane >> 4;
  const int qx = (int)gridDim.x >> 3;
  const int wg = ((int)blockIdx.x & 7) * qx + ((int)blockIdx.x >> 3);
  const int bx = wg / MT, by = wg - bx * MT;
  const int m0 = by * BM, n0 = bx * BN;
  const u16* Ab = A + (size_t)m0 * K;
  const u16* Bb = Bt + (size_t)n0 * K;

#define ABUF(c) (smem + (c) * ASZ)
#define BBUF(c) (smem + 2 * ASZ + (c) * BSZ)

  f32x4 acc[MI][NJF];
#pragma unroll
  for (int i = 0; i < MI; i++)
#pragma unroll
    for (int j = 0; j < NJF; j++)
#pragma unroll
      for (int r = 0; r < 4; r++) acc[i][j][r] = 0.f;

  auto stage = [&](int c, int kk) {
#pragma unroll
    for (int l = 0; l < BM / 64; l++) {
      const int u = tid + 512 * l, row = u >> 3, ch = u & 7;
      gload16(Ab + (size_t)row * K + ((ch ^ (row & 7)) << 3) + kk,
              ABUF(c) + (u << 4));
    }
#pragma unroll
    for (int l = 0; l < BN / 64; l++) {
      const int u = tid + 512 * l, row = u >> 3, ch = u & 7;
      gload16(Bb + (size_t)row * K + ((ch ^ (row & 7)) << 3) + kk,
              BBUF(c) + (u << 4));
    }
    if constexpr ((BN % 64) != 0) {
      const int u = (BN / 64) * 512 + (tid & 255), row = u >> 3, ch = u & 7;
      gload16(Bb + (size_t)row * K + ((ch ^ (row & 7)) << 3) + kk,
              BBUF(c) + (u << 4));
    }
  };

  const int NT = K >> 6;
  stage(0, 0);
  stage(1, 64);
  if constexpr (NL == 5) { WVMn(5); } else { WVMn(7); }
  BAR;

  bf16x8 af[MI][2], bf[NJF][2];
  for (int t = 0; t < NT; t++) {
    const int c = t & 1;
#pragma unroll
    for (int i = 0; i < MI; i++) {
      const int row = (wm * MI + i) * 16 + fr;
#pragma unroll
      for (int ks = 0; ks < 2; ks++)
        af[i][ks] = *(const bf16x8*)(ABUF(c) + row * 128 +
                                     ((((ks << 2) + fq) ^ (row & 7)) << 4));
    }
#pragma unroll
    for (int j = 0; j < NJF; j++) {
      const int row = (j * WN + wn) * 16 + fr;
#pragma unroll
      for (int ks = 0; ks < 2; ks++)
        bf[j][ks] = *(const bf16x8*)(BBUF(c) + row * 128 +
                                     ((((ks << 2) + fq) ^ (row & 7)) << 4));
    }
    WLG;
    BAR;                        // all waves done reading buf c
    int t2 = t + 2; if (t2 >= NT) t2 -= NT;
    stage(c, t2 << 6);
    if constexpr (NL == 5) { WVMn(5); } else { WVMn(7); }
    SP1;
#pragma unroll
    for (int j = 0; j < NJF; j++)
#pragma unroll
      for (int i = 0; i < MI; i++) {
        acc[i][j] = __builtin_amdgcn_mfma_f32_16x16x32_bf16(af[i][0], bf[j][0],
                                                            acc[i][j], 0, 0, 0);
        acc[i][j] = __builtin_amdgcn_mfma_f32_16x16x32_bf16(af[i][1], bf[j][1],
                                                            acc[i][j], 0, 0, 0);
      }
    SP0;
    BAR;
  }
  WVMn(0);

#pragma unroll
  for (int i = 0; i < MI; i++) {
    const int row0 = m0 + (wm * MI + i) * 16 + fq * 4;
#pragma unroll
    for (int j = 0; j < NJF; j++) {
      const int col = n0 + (j * WN + wn) * 16 + fr;
#pragma unroll
      for (int r = 0; r < 4; r++) {
        const size_t idx = (size_t)(row0 + r) * N + col;
        if constexpr (sizeof(CT) == 2) C[idx] = f2bf(acc[i][j][r]);
        else C[idx] = acc[i][j][r];
      }
    }
  }
#undef ABUF
#undef BBUF
}

// ---------------- Flash attention, causal GQA ----------------
// R13 compute structure; V staging DROPPED (V is L2/L3-resident: 512KB/group
// shared by 16 blocks — m169 lesson). K double-buffered in 32KB LDS -> 4
// blocks/CU. PV reads V B-fragments (16B, contiguous) straight from global;
// compiler-inserted vmcnt waits cover them; FIFO guarantees K(t+1) retired
// by PV end, so the end-of-iter vmcnt(0) is free (no true in-loop drain).
// Grid 1024 (one 32-row q-tile each), heavy-first LPT.
__global__ __launch_bounds__(256, 4)
void attn_fwd(const u16* __restrict__ Qr, const u16* __restrict__ Kr,
              const u16* __restrict__ Vt, u16* __restrict__ AO) {
  const int L = 2048, DH = 128;
  __shared__ u16 Ks[2][64 * 128];   // [buf][key][d], XOR-swizzled
  const int tid = threadIdx.x, lane = tid & 63, wid = tid >> 6;
  const int fr = lane & 15, fq = lane >> 4;
  const int t = 63 - (int)(blockIdx.x >> 4);     // heavy-first
  const int grp = blockIdx.x & 15;
  const int kvh = grp >> 1, b = grp & 1;
  const int h = kvh * 4 + wid;
  const int nk = (t >> 1) + 1;

  const u16* Kbase = Kr + (size_t)(b * 8 + kvh) * L * DH;
  const u16* Vbase = Vt + (size_t)(b * 8 + kvh) * DH * L;

  int Dly[4], kOff[4];
#pragma unroll
  for (int p = 0; p < 4; p++) {
    const int D = (tid + p * 256) * 16;
    Dly[p] = D;
    const int kr = D >> 8, kc = ((D >> 4) & 15) ^ (kr & 7);
    kOff[p] = kr * 128 + kc * 8;
  }

  auto stageK = [&](int kt, int bufi) {
    const int k0 = kt * 64;
#pragma unroll
    for (int p = 0; p < 4; p++)
      gload16(Kbase + (size_t)k0 * 128 + kOff[p], (char*)&Ks[bufi][0] + Dly[p]);
  };

  // Q fragments (both col-groups)
  bf16x8 qf[2][4];
#pragma unroll
  for (int g = 0; g < 2; g++) {
    const int qq = t * 32 + g * 16 + fr;
    const u16* qbase = Qr + ((size_t)(b * 32 + h) * L + qq) * DH + fq * 8;
#pragma unroll
    for (int dt = 0; dt < 4; dt++) qf[g][dt] = *(const bf16x8*)(qbase + dt * 32);
  }

  f32x4 o[2][8];
#pragma unroll
  for (int g = 0; g < 2; g++)
#pragma unroll
    for (int d = 0; d < 8; d++)
#pragma unroll
      for (int r = 0; r < 4; r++) o[g][d][r] = 0.f;
  float mrow[2] = {-__builtin_huge_valf(), -__builtin_huge_valf()};
  float lrow[2] = {0.f, 0.f};

  // prologue: stage K0; drain (Q + K0); barrier -> K0 visible to all waves
  stageK(0, 0);
  asm volatile("s_waitcnt vmcnt(0)" ::: "memory");
  __builtin_amdgcn_s_barrier();
  int cur = 0;

  for (int kt = 0; kt < nk; kt++) {
    if (kt + 1 < nk) stageK(kt + 1, cur ^ 1);    // prefetch next K tile

    const u16* KsB = &Ks[cur][0];
    const int k0 = kt * 64;

    f32x4 s4[2][4];
#pragma unroll
    for (int g = 0; g < 2; g++)
#pragma unroll
      for (int ni = 0; ni < 4; ni++)
#pragma unroll
        for (int r = 0; r < 4; r++) s4[g][ni][r] = 0.f;
    SP1;
#pragma unroll
    for (int ni = 0; ni < 4; ni++) {
      const int krow = ni * 16 + fr;
      const int sw = (krow & 7) << 4;
#pragma unroll
      for (int dt = 0; dt < 4; dt++) {
        const int off = (krow * 256 + dt * 64 + fq * 16) ^ sw;
        bf16x8 kf = *(const bf16x8*)((const char*)KsB + off);
        s4[0][ni] = __builtin_amdgcn_mfma_f32_16x16x32_bf16(kf, qf[0][dt], s4[0][ni], 0, 0, 0);
        s4[1][ni] = __builtin_amdgcn_mfma_f32_16x16x32_bf16(kf, qf[1][dt], s4[1][ni], 0, 0, 0);
      }
    }
    SP0;

    if (kt == nk - 1) {           // causal mask on diagonal tile
#pragma unroll
      for (int g = 0; g < 2; g++) {
        const int qq = t * 32 + g * 16 + fr;
#pragma unroll
        for (int ni = 0; ni < 4; ni++)
#pragma unroll
          for (int r = 0; r < 4; r++)
            if (k0 + ni * 16 + fq * 4 + r > qq) s4[g][ni][r] = -1e30f;
      }
    }

    bf16x8 pb[2][2];
#pragma unroll
    for (int g = 0; g < 2; g++) {
      float m0t = fmaxf(fmaxf(s4[g][0][0], s4[g][0][1]), fmaxf(s4[g][0][2], s4[g][0][3]));
      float m1t = fmaxf(fmaxf(s4[g][1][0], s4[g][1][1]), fmaxf(s4[g][1][2], s4[g][1][3]));
      float m2t = fmaxf(fmaxf(s4[g][2][0], s4[g][2][1]), fmaxf(s4[g][2][2], s4[g][2][3]));
      float m3t = fmaxf(fmaxf(s4[g][3][0], s4[g][3][1]), fmaxf(s4[g][3][2], s4[g][3][3]));
      float mt = fmaxf(fmaxf(m0t, m1t), fmaxf(m2t, m3t));
      mt = fmaxf(mt, __shfl_xor(mt, 16, 64));
      mt = fmaxf(mt, __shfl_xor(mt, 32, 64));

      if (!__all(mt <= mrow[g] + 8.f)) {         // defer-max (T13)
        const float mn = fmaxf(mrow[g], mt);
        const float corr = exp2f((mrow[g] - mn) * 1.44269504f);
        mrow[g] = mn;
        lrow[g] *= corr;
#pragma unroll
        for (int d = 0; d < 8; d++)
#pragma unroll
          for (int r = 0; r < 4; r++) o[g][d][r] *= corr;
      }

      const float ml = mrow[g] * 1.44269504f;
      float rp[4] = {0.f, 0.f, 0.f, 0.f};
#pragma unroll
      for (int ni = 0; ni < 4; ni++)
#pragma unroll
        for (int r = 0; r < 4; r++) {
          const float pv = exp2f(fmaf(s4[g][ni][r], 1.44269504f, -ml));
          s4[g][ni][r] = pv;
          rp[r] += pv;
        }
      float rs = (rp[0] + rp[1]) + (rp[2] + rp[3]);
      rs += __shfl_xor(rs, 16, 64);
      rs += __shfl_xor(rs, 32, 64);
      lrow[g] += rs;

      u32 pk[4][2];
#pragma unroll
      for (int ni = 0; ni < 4; ni++) {
        pk[ni][0] = __builtin_amdgcn_perm(__float_as_uint(s4[g][ni][1]),
                                          __float_as_uint(s4[g][ni][0]), 0x07060302u);
        pk[ni][1] = __builtin_amdgcn_perm(__float_as_uint(s4[g][ni][3]),
                                          __float_as_uint(s4[g][ni][2]), 0x07060302u);
      }
#pragma unroll
      for (int ks = 0; ks < 2; ks++) {
        auto s0 = __builtin_amdgcn_permlane32_swap(pk[2 * ks + 0][0],
                                                   pk[2 * ks + 1][0], false, false);
        auto s1 = __builtin_amdgcn_permlane32_swap(pk[2 * ks + 0][1],
                                                   pk[2 * ks + 1][1], false, false);
        auto q0 = __builtin_amdgcn_permlane16_swap(s0[0], s0[1], false, false);
        auto q1 = __builtin_amdgcn_permlane16_swap(s1[0], s1[1], false, false);
        union { u32 u[4]; bf16x8 v; } pbv;
        pbv.u[0] = q0[0]; pbv.u[1] = q1[0]; pbv.u[2] = q0[1]; pbv.u[3] = q1[1];
        pb[g][ks] = pbv.v;
      }
    }

    // PV: V fragments straight from global (16B contiguous per lane)
    const u16* Vk = Vbase + k0;
    SP1;
#pragma unroll
    for (int d = 0; d < 8; d++) {
      const u16* vrowp = Vk + (size_t)(d * 16 + fr) * L + fq * 8;
#pragma unroll
      for (int ks = 0; ks < 2; ks++) {
        bf16x8 vf = *(const bf16x8*)(vrowp + ks * 32);
        o[0][d] = __builtin_amdgcn_mfma_f32_16x16x32_bf16(vf, pb[0][ks], o[0][d], 0, 0, 0);
        o[1][d] = __builtin_amdgcn_mfma_f32_16x16x32_bf16(vf, pb[1][ks], o[1][d], 0, 0, 0);
      }
    }
    SP0;

    // V loads all retired (compiler waits) => K(kt+1) retired too (FIFO);
    // vmcnt(0) is free; barrier makes K(kt+1) visible + protects restage.
    asm volatile("s_waitcnt vmcnt(0)" ::: "memory");
    __builtin_amdgcn_s_barrier();
    cur ^= 1;
  }

  // epilogue: normalize and store O^T
#pragma unroll
  for (int g = 0; g < 2; g++) {
    const float inv = 1.f / lrow[g];
    const int qq = t * 32 + g * 16 + fr;
    u16* obase = AO + ((size_t)b * L + qq) * 4096 + h * 128 + fq * 4;
#pragma unroll
    for (int d = 0; d < 8; d++) {
      uint2 w;
      w.x = (u32)f2bf(o[g][d][0] * inv) | ((u32)f2bf(o[g][d][1] * inv) << 16);
      w.y = (u32)f2bf(o[g][d][2] * inv) | ((u32)f2bf(o[g][d][3] * inv) << 16);
      *(uint2*)(obase + d * 16) = w;
    }
  }
}

// ---------------- launcher ----------------
extern "C" void kernel_launch(void* const* d_in, const int* in_sizes, int n_in,
                              void* d_out, int out_size, void* d_ws, size_t ws_size,
                              hipStream_t stream) {
  const float* x    = (const float*)d_in[0];
  const float* Wq   = (const float*)d_in[1];
  const float* Wk   = (const float*)d_in[2];
  const float* Wv   = (const float*)d_in[3];
  const float* Wo   = (const float*)d_in[4];
  const float* qw   = (const float*)d_in[5];
  const float* kw   = (const float*)d_in[6];
  const float* cosp = (const float*)d_in[7];
  const float* sinp = (const float*)d_in[8];
  float* out = (float*)d_out;
  char* ws = (char*)d_ws;

  u16* xb    = (u16*)(ws);                 // 4096x2560 bf16
  u16* WqkvT = (u16*)(ws + 20971520);      // 6144x2560 bf16
  u16* WoT   = (u16*)(ws + 52428800);      // 2560x4096 bf16
  u16* QKV   = (u16*)(ws + 73400320);      // 4096x6144 bf16
  u16* AO    = QKV;                        // alias: QKV dead before attn writes
  u16* Qrr   = (u16*)(ws + 123731968);
  u16* Krr   = (u16*)(ws + 157286400);
  u16* Vtt   = (u16*)(ws + 165675008);

  hipFuncSetAttribute(reinterpret_cast<const void*>(&gemmT<4, 128, 192, 2, 4, u16>),
                      hipFuncAttributeMaxDynamicSharedMemorySize, 81920);
  hipFuncSetAttribute(reinterpret_cast<const void*>(&gemmT<4, 128, 160, 4, 2, float>),
                      hipFuncAttributeMaxDynamicSharedMemorySize, 73728);

  cvt_f32_bf16<<<10240, 256, 0, stream>>>((const float4*)x, (uint2*)xb, 2621440);
  transpose_all<<<25600, 256, 0, stream>>>(Wq, Wk, Wv, Wo, WqkvT, WoT);

  // QKV: M=4096 (32 x 128) x N=6144 (32 x 192) -> 1024 blocks, 2 blk/CU (R8)
  gemmT<4, 128, 192, 2, 4, u16><<<1024, 512, 81920, stream>>>(xb, WqkvT, QKV, 6144, 2560, 32);

  norm_rope<<<40960, 256, 0, stream>>>(QKV, qw, kw, cosp, sinp, Qrr, Krr);
  transpose_v<<<dim3(64, 4, 16), 256, 0, stream>>>(QKV, Vtt);

  // attn: 64 q-tiles x 16 kv-groups = 1024 blocks, heavy-first, 4 blk/CU
  attn_fwd<<<dim3(1024), 256, 0, stream>>>(Qrr, Krr, Vtt, AO);

  // O-proj: M=4096 (32 x 128) x N=2560 (16 x 160) -> 512 blocks, 2 blk/CU (R8)
  gemmT<4, 128, 160, 4, 2, float><<<512, 512, 73728, stream>>>(AO, WoT, out, 2560, 4096, 32);
}

// Round 16
// 405.569 us; speedup vs baseline: 1.8312x; 1.8312x over previous
//
#include <hip/hip_runtime.h>

typedef unsigned short u16;
typedef unsigned int u32;
using bf16x8 = __attribute__((ext_vector_type(8))) __bf16;
using f32x4  = __attribute__((ext_vector_type(4))) float;

typedef const void __attribute__((address_space(1)))* gas1p;
typedef void __attribute__((address_space(3)))* las3p;

__device__ __forceinline__ void gload16(const void* g, void* l) {
  __builtin_amdgcn_global_load_lds((gas1p)g, (las3p)l, 16, 0, 0);
}

__device__ __forceinline__ u16 f2bf(float f) {
  union { float f; unsigned u; } v; v.f = f;
  unsigned r = v.u + 0x7FFFu + ((v.u >> 16) & 1u);
  return (u16)(r >> 16);
}
__device__ __forceinline__ float bf2f(u16 h) {
  union { unsigned u; float f; } v; v.u = ((unsigned)h) << 16;
  return v.f;
}

// ---------------- x fp32 -> bf16 ----------------
__global__ __launch_bounds__(256)
void cvt_f32_bf16(const float4* __restrict__ in, uint2* __restrict__ out, int n4) {
  int i = blockIdx.x * 256 + threadIdx.x;
  if (i >= n4) return;
  float4 v = in[i];
  uint2 o;
  o.x = (unsigned)f2bf(v.x) | ((unsigned)f2bf(v.y) << 16);
  o.y = (unsigned)f2bf(v.z) | ((unsigned)f2bf(v.w) << 16);
  out[i] = o;
}

// ------- fused W transposes: Wq/Wk/Wv -> WqkvT, Wo -> WoT (one launch) -----
__global__ __launch_bounds__(256)
void transpose_all(const float* __restrict__ Wq, const float* __restrict__ Wk,
                   const float* __restrict__ Wv, const float* __restrict__ Wo,
                   u16* __restrict__ WqkvT, u16* __restrict__ WoT) {
  __shared__ float tile[32][33];
  const int bid = blockIdx.x;
  const float* in; u16* out; int C, R, bx, by;
  if (bid < 10240)      { in = Wq; out = WqkvT;                         R = 2560; C = 4096; bx = bid % 128;           by = bid / 128; }
  else if (bid < 12800) { in = Wk; out = WqkvT + (size_t)4096 * 2560;   R = 2560; C = 1024; bx = (bid - 10240) % 32;  by = (bid - 10240) / 32; }
  else if (bid < 15360) { in = Wv; out = WqkvT + (size_t)5120 * 2560;   R = 2560; C = 1024; bx = (bid - 12800) % 32;  by = (bid - 12800) / 32; }
  else                  { in = Wo; out = WoT;                           R = 4096; C = 2560; bx = (bid - 15360) % 80;  by = (bid - 15360) / 80; }
  const int tx = threadIdx.x & 31, ty = threadIdx.x >> 5;
  const int r0 = by * 32, c0 = bx * 32;
#pragma unroll
  for (int i = 0; i < 4; i++)
    tile[ty + i * 8][tx] = in[(size_t)(r0 + ty + i * 8) * C + c0 + tx];
  __syncthreads();
#pragma unroll
  for (int i = 0; i < 4; i++)
    out[(size_t)(c0 + ty + i * 8) * R + r0 + tx] = f2bf(tile[tx][ty + i * 8]);
}

// ---------------- V slice of QKV -> Vt (b,kv,d,l) bf16 ----------------
__global__ __launch_bounds__(256)
void transpose_v(const u16* __restrict__ QKV, u16* __restrict__ Vt) {
  __shared__ u16 tile[32][34];
  const int tx = threadIdx.x & 31, ty = threadIdx.x >> 5;
  const int l0 = blockIdx.x * 32, d0 = blockIdx.y * 32;
  const int bkv = blockIdx.z;
  const int b = bkv >> 3, kvh = bkv & 7;
#pragma unroll
  for (int i = 0; i < 4; i++)
    tile[ty + i * 8][tx] =
        QKV[(size_t)(b * 2048 + l0 + ty + i * 8) * 6144 + 5120 + kvh * 128 + d0 + tx];
  __syncthreads();
#pragma unroll
  for (int i = 0; i < 4; i++)
    Vt[((size_t)bkv * 128 + d0 + ty + i * 8) * 2048 + l0 + tx] = tile[tx][ty + i * 8];
}

// ---------------- RMSNorm + RoPE (+1/sqrt(128) folded into Q) ----------------
__global__ __launch_bounds__(256)
void norm_rope(const u16* __restrict__ QKV, const float* __restrict__ qw,
               const float* __restrict__ kw, const float* __restrict__ cosp,
               const float* __restrict__ sinp, u16* __restrict__ Qr,
               u16* __restrict__ Kr) {
  const int rid = blockIdx.x * 4 + (threadIdx.x >> 6);
  const int lane = threadIdx.x & 63;
  const int head = rid % 40;
  const int bl = rid / 40;               // b*2048 + l
  const int b = bl >> 11, l = bl & 2047;
  const u16* src; const float* w; u16* dst; float scale;
  if (head < 32) {
    src = QKV + (size_t)bl * 6144 + head * 128;
    w = qw;
    dst = Qr + ((size_t)(b * 32 + head) * 2048 + l) * 128;
    scale = 0.08838834764831845f;        // 1/sqrt(128)
  } else {
    const int kvh = head - 32;
    src = QKV + (size_t)bl * 6144 + 4096 + kvh * 128;
    w = kw;
    dst = Kr + ((size_t)(b * 8 + kvh) * 2048 + l) * 128;
    scale = 1.0f;
  }
  float lo = bf2f(src[lane]);
  float hi = bf2f(src[lane + 64]);
  float ss = lo * lo + hi * hi;
#pragma unroll
  for (int m = 1; m < 64; m <<= 1) ss += __shfl_xor(ss, m, 64);
  const float rstd = rsqrtf(ss * (1.0f / 128.0f) + 1e-6f) * scale;
  const float nlo = lo * rstd * w[lane];
  const float nhi = hi * rstd * w[lane + 64];
  const float* cb = cosp + (size_t)bl * 128;
  const float* sb = sinp + (size_t)bl * 128;
  dst[lane]      = f2bf(nlo * cb[lane]      - nhi * sb[lane]);
  dst[lane + 64] = f2bf(nhi * cb[lane + 64] + nlo * sb[lane + 64]);
}

// ====== BK=64 GEMM, 1 compute phase/K-tile (R8-proven structure) ===========
#define BAR __builtin_amdgcn_s_barrier()
#define WLG { asm volatile("s_waitcnt lgkmcnt(0)" ::: "memory");            \
              __builtin_amdgcn_sched_barrier(0); }
#define WVMn(n) asm volatile("s_waitcnt vmcnt(" #n ")" ::: "memory")
#define SP1 __builtin_amdgcn_s_setprio(1)
#define SP0 __builtin_amdgcn_s_setprio(0)

template <int MINW, int BM, int BN, int WM, int WN, typename CT>
__global__ __launch_bounds__(512, MINW)
void gemmT(const u16* __restrict__ A, const u16* __restrict__ Bt,
           CT* __restrict__ C, int N, int K, int MT) {
  extern __shared__ char smem[];
  constexpr int ASZ = BM * 128;
  constexpr int BSZ = BN * 128;
  constexpr int MI = BM / WM / 16;
  constexpr int NJF = BN / WN / 16;
  constexpr int NL = BM / 64 + (BN + 63) / 64;
  const int tid = threadIdx.x, lane = tid & 63, wid = tid >> 6;
  const int wm = wid / WN, wn = wid % WN;
  const int fr = lane & 15, fq = lane >> 4;
  const int qx = (int)gridDim.x >> 3;
  const int wg = ((int)blockIdx.x & 7) * qx + ((int)blockIdx.x >> 3);
  const int bx = wg / MT, by = wg - bx * MT;
  const int m0 = by * BM, n0 = bx * BN;
  const u16* Ab = A + (size_t)m0 * K;
  const u16* Bb = Bt + (size_t)n0 * K;

#define ABUF(c) (smem + (c) * ASZ)
#define BBUF(c) (smem + 2 * ASZ + (c) * BSZ)

  f32x4 acc[MI][NJF];
#pragma unroll
  for (int i = 0; i < MI; i++)
#pragma unroll
    for (int j = 0; j < NJF; j++)
#pragma unroll
      for (int r = 0; r < 4; r++) acc[i][j][r] = 0.f;

  auto stage = [&](int c, int kk) {
#pragma unroll
    for (int l = 0; l < BM / 64; l++) {
      const int u = tid + 512 * l, row = u >> 3, ch = u & 7;
      gload16(Ab + (size_t)row * K + ((ch ^ (row & 7)) << 3) + kk,
              ABUF(c) + (u << 4));
    }
#pragma unroll
    for (int l = 0; l < BN / 64; l++) {
      const int u = tid + 512 * l, row = u >> 3, ch = u & 7;
      gload16(Bb + (size_t)row * K + ((ch ^ (row & 7)) << 3) + kk,
              BBUF(c) + (u << 4));
    }
    if constexpr ((BN % 64) != 0) {
      const int u = (BN / 64) * 512 + (tid & 255), row = u >> 3, ch = u & 7;
      gload16(Bb + (size_t)row * K + ((ch ^ (row & 7)) << 3) + kk,
              BBUF(c) + (u << 4));
    }
  };

  const int NT = K >> 6;
  stage(0, 0);
  stage(1, 64);
  if constexpr (NL == 5) { WVMn(5); } else { WVMn(7); }
  BAR;

  bf16x8 af[MI][2], bf[NJF][2];
  for (int t = 0; t < NT; t++) {
    const int c = t & 1;
#pragma unroll
    for (int i = 0; i < MI; i++) {
      const int row = (wm * MI + i) * 16 + fr;
#pragma unroll
      for (int ks = 0; ks < 2; ks++)
        af[i][ks] = *(const bf16x8*)(ABUF(c) + row * 128 +
                                     ((((ks << 2) + fq) ^ (row & 7)) << 4));
    }
#pragma unroll
    for (int j = 0; j < NJF; j++) {
      const int row = (j * WN + wn) * 16 + fr;
#pragma unroll
      for (int ks = 0; ks < 2; ks++)
        bf[j][ks] = *(const bf16x8*)(BBUF(c) + row * 128 +
                                     ((((ks << 2) + fq) ^ (row & 7)) << 4));
    }
    WLG;
    BAR;                        // all waves done reading buf c
    int t2 = t + 2; if (t2 >= NT) t2 -= NT;
    stage(c, t2 << 6);
    if constexpr (NL == 5) { WVMn(5); } else { WVMn(7); }
    SP1;
#pragma unroll
    for (int j = 0; j < NJF; j++)
#pragma unroll
      for (int i = 0; i < MI; i++) {
        acc[i][j] = __builtin_amdgcn_mfma_f32_16x16x32_bf16(af[i][0], bf[j][0],
                                                            acc[i][j], 0, 0, 0);
        acc[i][j] = __builtin_amdgcn_mfma_f32_16x16x32_bf16(af[i][1], bf[j][1],
                                                            acc[i][j], 0, 0, 0);
      }
    SP0;
    BAR;
  }
  WVMn(0);

#pragma unroll
  for (int i = 0; i < MI; i++) {
    const int row0 = m0 + (wm * MI + i) * 16 + fq * 4;
#pragma unroll
    for (int j = 0; j < NJF; j++) {
      const int col = n0 + (j * WN + wn) * 16 + fr;
#pragma unroll
      for (int r = 0; r < 4; r++) {
        const size_t idx = (size_t)(row0 + r) * N + col;
        if constexpr (sizeof(CT) == 2) C[idx] = f2bf(acc[i][j][r]);
        else C[idx] = acc[i][j][r];
      }
    }
  }
#undef ABUF
#undef BBUF
}

// ---------------- Flash attention, causal GQA (R14-proven: R3 + setprio + tree)
__global__ __launch_bounds__(256, 2)
void attn_fwd(const u16* __restrict__ Qr, const u16* __restrict__ Kr,
              const u16* __restrict__ Vt, u16* __restrict__ AO) {
  const int L = 2048, DH = 128;
  __shared__ u16 Ks[2][64 * 128];   // [buf][key][d], XOR-swizzled
  __shared__ u16 Vs[2][128 * 64];   // [buf][d][key], XOR-swizzled
  const int tid = threadIdx.x, lane = tid & 63, wid = tid >> 6;
  const int fr = lane & 15, fq = lane >> 4;
  const int j = blockIdx.x >> 4;           // q-tile pair index [0,32)
  const int grp = blockIdx.x & 15;
  const int kvh = grp >> 1, b = grp & 1;
  const int h = kvh * 4 + wid;

  const u16* Kbase = Kr + (size_t)(b * 8 + kvh) * L * DH;
  const u16* Vbase = Vt + (size_t)(b * 8 + kvh) * DH * L;

  int Dly[4], kOff[4], vOff[4];
#pragma unroll
  for (int p = 0; p < 4; p++) {
    const int D = (tid + p * 256) * 16;
    Dly[p] = D;
    const int kr = D >> 8, kc = ((D >> 4) & 15) ^ (kr & 7);
    kOff[p] = kr * 128 + kc * 8;
    const int vr = D >> 7, vc = ((D >> 4) & 7) ^ (vr & 7);
    vOff[p] = vr * 2048 + vc * 8;
  }

  auto stage = [&](int kt, int bufi) {
    const int k0 = kt * 64;
#pragma unroll
    for (int p = 0; p < 4; p++) {
      gload16(Kbase + (size_t)k0 * 128 + kOff[p], (char*)&Ks[bufi][0] + Dly[p]);
      gload16(Vbase + k0 + vOff[p], (char*)&Vs[bufi][0] + Dly[p]);
    }
  };

  for (int half = 0; half < 2; half++) {
    const int t = half ? 63 - j : j;
    const int nk = (t >> 1) + 1;

    bf16x8 qf[2][4];
#pragma unroll
    for (int g = 0; g < 2; g++) {
      const int qq = t * 32 + g * 16 + fr;
      const u16* qbase = Qr + ((size_t)(b * 32 + h) * L + qq) * DH + fq * 8;
#pragma unroll
      for (int dt = 0; dt < 4; dt++) qf[g][dt] = *(const bf16x8*)(qbase + dt * 32);
    }
    asm volatile("s_waitcnt vmcnt(0)" ::: "memory");

    f32x4 o[2][8];
#pragma unroll
    for (int g = 0; g < 2; g++)
#pragma unroll
      for (int d = 0; d < 8; d++)
#pragma unroll
        for (int r = 0; r < 4; r++) o[g][d][r] = 0.f;
    float mrow[2] = {-__builtin_huge_valf(), -__builtin_huge_valf()};
    float lrow[2] = {0.f, 0.f};

    __builtin_amdgcn_s_barrier();
    stage(0, 0);
    int cur = 0;

    for (int kt = 0; kt < nk; kt++) {
      if (kt + 1 < nk) {
        stage(kt + 1, cur ^ 1);
        asm volatile("s_waitcnt vmcnt(8)" ::: "memory");
      } else {
        asm volatile("s_waitcnt vmcnt(0)" ::: "memory");
      }
      __builtin_amdgcn_s_barrier();

      const u16* KsB = &Ks[cur][0];
      const u16* VsB = &Vs[cur][0];
      const int k0 = kt * 64;

      f32x4 s4[2][4];
#pragma unroll
      for (int g = 0; g < 2; g++)
#pragma unroll
        for (int ni = 0; ni < 4; ni++)
#pragma unroll
          for (int r = 0; r < 4; r++) s4[g][ni][r] = 0.f;
      SP1;
#pragma unroll
      for (int ni = 0; ni < 4; ni++) {
        const int krow = ni * 16 + fr;
        const int sw = (krow & 7) << 4;
#pragma unroll
        for (int dt = 0; dt < 4; dt++) {
          const int off = (krow * 256 + dt * 64 + fq * 16) ^ sw;
          bf16x8 kf = *(const bf16x8*)((const char*)KsB + off);
          s4[0][ni] = __builtin_amdgcn_mfma_f32_16x16x32_bf16(kf, qf[0][dt], s4[0][ni], 0, 0, 0);
          s4[1][ni] = __builtin_amdgcn_mfma_f32_16x16x32_bf16(kf, qf[1][dt], s4[1][ni], 0, 0, 0);
        }
      }
      SP0;

      if (kt == nk - 1) {
#pragma unroll
        for (int g = 0; g < 2; g++) {
          const int qq = t * 32 + g * 16 + fr;
#pragma unroll
          for (int ni = 0; ni < 4; ni++)
#pragma unroll
            for (int r = 0; r < 4; r++)
              if (k0 + ni * 16 + fq * 4 + r > qq) s4[g][ni][r] = -1e30f;
        }
      }

      bf16x8 pb[2][2];
#pragma unroll
      for (int g = 0; g < 2; g++) {
        float m0t = fmaxf(fmaxf(s4[g][0][0], s4[g][0][1]), fmaxf(s4[g][0][2], s4[g][0][3]));
        float m1t = fmaxf(fmaxf(s4[g][1][0], s4[g][1][1]), fmaxf(s4[g][1][2], s4[g][1][3]));
        float m2t = fmaxf(fmaxf(s4[g][2][0], s4[g][2][1]), fmaxf(s4[g][2][2], s4[g][2][3]));
        float m3t = fmaxf(fmaxf(s4[g][3][0], s4[g][3][1]), fmaxf(s4[g][3][2], s4[g][3][3]));
        float mt = fmaxf(fmaxf(m0t, m1t), fmaxf(m2t, m3t));
        mt = fmaxf(mt, __shfl_xor(mt, 16, 64));
        mt = fmaxf(mt, __shfl_xor(mt, 32, 64));

        if (!__all(mt <= mrow[g] + 8.f)) {
          const float mn = fmaxf(mrow[g], mt);
          const float corr = exp2f((mrow[g] - mn) * 1.44269504f);
          mrow[g] = mn;
          lrow[g] *= corr;
#pragma unroll
          for (int d = 0; d < 8; d++)
#pragma unroll
            for (int r = 0; r < 4; r++) o[g][d][r] *= corr;
        }

        const float ml = mrow[g] * 1.44269504f;
        float rp[4] = {0.f, 0.f, 0.f, 0.f};
#pragma unroll
        for (int ni = 0; ni < 4; ni++)
#pragma unroll
          for (int r = 0; r < 4; r++) {
            const float pv = exp2f(fmaf(s4[g][ni][r], 1.44269504f, -ml));
            s4[g][ni][r] = pv;
            rp[r] += pv;
          }
        float rs = (rp[0] + rp[1]) + (rp[2] + rp[3]);
        rs += __shfl_xor(rs, 16, 64);
        rs += __shfl_xor(rs, 32, 64);
        lrow[g] += rs;

        u32 pk[4][2];
#pragma unroll
        for (int ni = 0; ni < 4; ni++) {
          pk[ni][0] = __builtin_amdgcn_perm(__float_as_uint(s4[g][ni][1]),
                                            __float_as_uint(s4[g][ni][0]), 0x07060302u);
          pk[ni][1] = __builtin_amdgcn_perm(__float_as_uint(s4[g][ni][3]),
                                            __float_as_uint(s4[g][ni][2]), 0x07060302u);
        }
#pragma unroll
        for (int ks = 0; ks < 2; ks++) {
          auto s0 = __builtin_amdgcn_permlane32_swap(pk[2 * ks + 0][0],
                                                     pk[2 * ks + 1][0], false, false);
          auto s1 = __builtin_amdgcn_permlane32_swap(pk[2 * ks + 0][1],
                                                     pk[2 * ks + 1][1], false, false);
          auto q0 = __builtin_amdgcn_permlane16_swap(s0[0], s0[1], false, false);
          auto q1 = __builtin_amdgcn_permlane16_swap(s1[0], s1[1], false, false);
          union { u32 u[4]; bf16x8 v; } pbv;
          pbv.u[0] = q0[0]; pbv.u[1] = q1[0]; pbv.u[2] = q0[1]; pbv.u[3] = q1[1];
          pb[g][ks] = pbv.v;
        }
      }

      SP1;
#pragma unroll
      for (int d = 0; d < 8; d++) {
        const int vrow = d * 16 + fr;
        const int sw = (vrow & 7) << 4;
#pragma unroll
        for (int ks = 0; ks < 2; ks++) {
          const int off = (vrow * 128 + ks * 64 + fq * 16) ^ sw;
          bf16x8 vf = *(const bf16x8*)((const char*)VsB + off);
          o[0][d] = __builtin_amdgcn_mfma_f32_16x16x32_bf16(vf, pb[0][ks], o[0][d], 0, 0, 0);
          o[1][d] = __builtin_amdgcn_mfma_f32_16x16x32_bf16(vf, pb[1][ks], o[1][d], 0, 0, 0);
        }
      }
      SP0;
      __builtin_amdgcn_s_barrier();
      cur ^= 1;
    }

#pragma unroll
    for (int g = 0; g < 2; g++) {
      const float inv = 1.f / lrow[g];
      const int qq = t * 32 + g * 16 + fr;
      u16* obase = AO + ((size_t)b * L + qq) * 4096 + h * 128 + fq * 4;
#pragma unroll
      for (int d = 0; d < 8; d++) {
        uint2 w;
        w.x = (u32)f2bf(o[g][d][0] * inv) | ((u32)f2bf(o[g][d][1] * inv) << 16);
        w.y = (u32)f2bf(o[g][d][2] * inv) | ((u32)f2bf(o[g][d][3] * inv) << 16);
        *(uint2*)(obase + d * 16) = w;
      }
    }
  }
}

// ---------------- launcher ----------------
extern "C" void kernel_launch(void* const* d_in, const int* in_sizes, int n_in,
                              void* d_out, int out_size, void* d_ws, size_t ws_size,
                              hipStream_t stream) {
  const float* x    = (const float*)d_in[0];
  const float* Wq   = (const float*)d_in[1];
  const float* Wk   = (const float*)d_in[2];
  const float* Wv   = (const float*)d_in[3];
  const float* Wo   = (const float*)d_in[4];
  const float* qw   = (const float*)d_in[5];
  const float* kw   = (const float*)d_in[6];
  const float* cosp = (const float*)d_in[7];
  const float* sinp = (const float*)d_in[8];
  float* out = (float*)d_out;
  char* ws = (char*)d_ws;

  u16* xb    = (u16*)(ws);                 // 4096x2560 bf16
  u16* WqkvT = (u16*)(ws + 20971520);      // 6144x2560 bf16
  u16* WoT   = (u16*)(ws + 52428800);      // 2560x4096 bf16
  u16* QKV   = (u16*)(ws + 73400320);      // 4096x6144 bf16
  u16* AO    = QKV;                        // alias: QKV dead before attn writes
  u16* Qrr   = (u16*)(ws + 123731968);
  u16* Krr   = (u16*)(ws + 157286400);
  u16* Vtt   = (u16*)(ws + 165675008);

  hipFuncSetAttribute(reinterpret_cast<const void*>(&gemmT<4, 128, 192, 2, 4, u16>),
                      hipFuncAttributeMaxDynamicSharedMemorySize, 81920);
  hipFuncSetAttribute(reinterpret_cast<const void*>(&gemmT<4, 128, 160, 4, 2, float>),
                      hipFuncAttributeMaxDynamicSharedMemorySize, 73728);

  cvt_f32_bf16<<<10240, 256, 0, stream>>>((const float4*)x, (uint2*)xb, 2621440);
  transpose_all<<<25600, 256, 0, stream>>>(Wq, Wk, Wv, Wo, WqkvT, WoT);

  // QKV: M=4096 (32 x 128) x N=6144 (32 x 192) -> 1024 blocks, 2 blk/CU (R8)
  gemmT<4, 128, 192, 2, 4, u16><<<1024, 512, 81920, stream>>>(xb, WqkvT, QKV, 6144, 2560, 32);

  norm_rope<<<40960, 256, 0, stream>>>(QKV, qw, kw, cosp, sinp, Qrr, Krr);
  transpose_v<<<dim3(64, 4, 16), 256, 0, stream>>>(QKV, Vtt);

  // attn: R14-proven structure, 512 blocks (balanced q-tile pairs)
  attn_fwd<<<dim3(512), 256, 0, stream>>>(Qrr, Krr, Vtt, AO);

  // O-proj: M=4096 (32 x 128) x N=2560 (16 x 160) -> 512 blocks, 2 blk/CU (R8)
  gemmT<4, 128, 160, 4, 2, float><<<512, 512, 73728, stream>>>(AO, WoT, out, 2560, 4096, 32);
}